// Round 8
// baseline (108.350 us; speedup 1.0000x reference)
//
#include <hip/hip_runtime.h>

typedef unsigned short u16;
typedef unsigned int u32;
typedef __attribute__((ext_vector_type(8))) short short8;
typedef __attribute__((ext_vector_type(16))) float f32x16;
typedef __attribute__((ext_vector_type(4))) float f32x4;
typedef __attribute__((ext_vector_type(4))) unsigned int u32x4;

#define H 256
#define D 128

// Fragment-chunk layout for normalized bf16 embeddings (consumed by maxsim):
//   elem index = tile*4096 + kc*512 + (l31*2 + lg2)*8 + j
//   holds Y[token = tile*32 + l31][k = kc*16 + lg2*8 + j]
// A wave's 64 lanes (slot = l31*2+lg2) load/store 1024 CONTIGUOUS bytes per kc.

union V16 { u32x4 u; short8 s; f32x4 f; };

static __device__ inline u32 bf16pk_rne(float a, float b) {
    u32 ua = __float_as_uint(a), ub = __float_as_uint(b);
    ua = ua + 0x7FFFu + ((ua >> 16) & 1u);
    ub = ub + 0x7FFFu + ((ub >> 16) & 1u);
    return (ua >> 16) | (ub & 0xFFFF0000u);
}

// ---------------- prep_w: W (fp32 [H][D]) -> bf16 hi/lo A-fragments ----------
__global__ __launch_bounds__(256) void prep_w(
    const float* __restrict__ W, u16* __restrict__ whi, u16* __restrict__ wlo)
{
    const int g   = blockIdx.x * 256 + threadIdx.x;   // 0..4095
    const int slot = g & 63;
    const int kc  = (g >> 6) & 15;
    const int nt  = g >> 10;
    const int l31 = slot >> 1;
    const int lg2 = slot & 1;
    const int k0  = kc * 16 + lg2 * 8;
    const int n   = nt * 32 + l31;

    u32 hw[4], lw[4];
    #pragma unroll
    for (int p = 0; p < 4; ++p) {
        float a = W[(size_t)(k0 + 2*p)     * D + n];
        float b = W[(size_t)(k0 + 2*p + 1) * D + n];
        u32 ua = __float_as_uint(a), ub = __float_as_uint(b);
        u32 ha = ua & 0xFFFF0000u,   hb = ub & 0xFFFF0000u;
        hw[p] = (ua >> 16) | hb;                       // hi = truncation
        float la = a - __uint_as_float(ha);
        float lb = b - __uint_as_float(hb);
        u32 ra = __float_as_uint(la); ra += 0x7FFFu + ((ra >> 16) & 1u);
        u32 rb = __float_as_uint(lb); rb += 0x7FFFu + ((rb >> 16) & 1u);
        lw[p] = (ra >> 16) | (rb & 0xFFFF0000u);       // lo = RNE bf16
    }
    u32x4 hv = {hw[0], hw[1], hw[2], hw[3]};
    u32x4 lv = {lw[0], lw[1], lw[2], lw[3]};
    *(u32x4*)&whi[(size_t)g * 8] = hv;
    *(u32x4*)&wlo[(size_t)g * 8] = lv;
}

// ---------------- proj v4: 1-wave blocks (grid 640 -> all 256 CUs) -----------
// Each wave: 32 tokens. X staged wave-private in LDS (swizzled 16B slots).
__global__ __launch_bounds__(64) void proj_mfma(
    const float* __restrict__ Xq, const float* __restrict__ Xd,
    const float* __restrict__ bias,
    const u16* __restrict__ whi, const u16* __restrict__ wlo,
    u16* __restrict__ outq, u16* __restrict__ outd)
{
    __shared__ float xst[32][256];      // 32 KB; slot s of row t holds slot s^(t&7)
    const int lane = threadIdx.x & 63;
    const int l31  = lane & 31;
    const int hi   = lane >> 5;
    const int slot = l31 * 2 + hi;

    const float* X; u16* out; int trow0;
    if (blockIdx.x < 128) { X = Xq; out = outq; trow0 = blockIdx.x * 32; }
    else { X = Xd; out = outd; trow0 = (blockIdx.x - 128) * 32; }

    // ---- stage: 32 rows x 1 KB, coalesced; wave-private (no barrier) ----
    {
        const float* xs0 = X + (size_t)trow0 * H;
        #pragma unroll
        for (int t = 0; t < 32; ++t) {
            f32x4 v = *(const f32x4*)&xs0[(size_t)t * H + lane * 4];
            int sl = lane ^ (t & 7);
            *(f32x4*)&xst[t][sl * 4] = v;
        }
    }

    f32x16 acc[4];
    #pragma unroll
    for (int nt = 0; nt < 4; ++nt) acc[nt] = (f32x16){0.f};

    #pragma unroll
    for (int kc = 0; kc < 16; ++kc) {
        const int g = kc * 4 + hi * 2;
        const int sw = l31 & 7;
        f32x4 va = *(const f32x4*)&xst[l31][((g ^ sw) << 2)];
        f32x4 vb = *(const f32x4*)&xst[l31][(((g + 1) ^ sw) << 2)];
        float e[8];
        #pragma unroll
        for (int i = 0; i < 4; ++i) { e[i] = va[i]; e[i + 4] = vb[i]; }

        V16 xh, xl;
        u32 xhu[4], xlu[4];
        #pragma unroll
        for (int p = 0; p < 4; ++p) {
            u32 u0 = __float_as_uint(e[2*p]), u1 = __float_as_uint(e[2*p+1]);
            u32 h0 = u0 & 0xFFFF0000u,        h1 = u1 & 0xFFFF0000u;
            xhu[p] = (u0 >> 16) | h1;                          // hi = trunc
            float l0 = e[2*p]   - __uint_as_float(h0);         // exact residual
            float l1 = e[2*p+1] - __uint_as_float(h1);
            xlu[p] = (__float_as_uint(l0) >> 16) |
                     (__float_as_uint(l1) & 0xFFFF0000u);
        }
        xh.u = (u32x4){xhu[0], xhu[1], xhu[2], xhu[3]};
        xl.u = (u32x4){xlu[0], xlu[1], xlu[2], xlu[3]};

        #pragma unroll
        for (int nt = 0; nt < 4; ++nt) {
            V16 wh, wl;
            const size_t fo = (size_t)((nt * 16 + kc) * 64 + slot) * 8;
            wh.u = *(const u32x4*)&whi[fo];
            wl.u = *(const u32x4*)&wlo[fo];
            acc[nt] = __builtin_amdgcn_mfma_f32_32x32x16_bf16(wh.s, xh.s, acc[nt], 0, 0, 0);
            acc[nt] = __builtin_amdgcn_mfma_f32_32x32x16_bf16(wl.s, xh.s, acc[nt], 0, 0, 0);
            acc[nt] = __builtin_amdgcn_mfma_f32_32x32x16_bf16(wh.s, xl.s, acc[nt], 0, 0, 0);
        }
    }

    // bias + sum-sq (lane holds 64 of token l31's 128 outputs; partner has rest)
    float ss = 0.f;
    #pragma unroll
    for (int nt = 0; nt < 4; ++nt) {
        #pragma unroll
        for (int q = 0; q < 4; ++q) {
            f32x4 b4 = *(const f32x4*)&bias[nt * 32 + q * 8 + hi * 4];
            #pragma unroll
            for (int i = 0; i < 4; ++i) {
                float v = acc[nt][q*4+i] + b4[i];
                acc[nt][q*4+i] = v;
                ss += v * v;
            }
        }
    }
    ss += __shfl_xor(ss, 32);
    const float inv = 1.0f / fmaxf(sqrtf(ss), 1e-12f);

    // pack bf16, pair-exchange (l <-> l+32), coalesced frag-layout stores
    const size_t base = (size_t)(trow0 >> 5) * 4096;
    #pragma unroll
    for (int nt = 0; nt < 4; ++nt) {
        #pragma unroll
        for (int q = 0; q < 4; ++q) {
            float v0 = acc[nt][q*4+0] * inv, v1 = acc[nt][q*4+1] * inv;
            float v2 = acc[nt][q*4+2] * inv, v3 = acc[nt][q*4+3] * inv;
            u32 p0 = bf16pk_rne(v0, v1), p1 = bf16pk_rne(v2, v3);
            u32 r0 = __shfl_xor(p0, 32), r1 = __shfl_xor(p1, 32);
            if ((q & 1) == hi) {
                const int kcs = nt * 2 + (q >> 1);
                u32x4 ck;
                if (hi == 0) ck = (u32x4){p0, p1, r0, r1};
                else         ck = (u32x4){r0, r1, p0, p1};
                *(u32x4*)&out[base + (size_t)kcs * 512 + (size_t)slot * 8] = ck;
            }
        }
    }
}

// ---------------- max-sim v6: 4 qb x 4 db, Q in LDS, wave owns full db ------
// block: 256 threads (4 waves). grid = 32 qg x 32 dg = 1024.
// Wave w handles doc batch dg*4+w entirely (4 tiles = 128 doc tokens), so the
// token-max completes in-wave: no cross-wave reduce, no smax LDS, 1 barrier.
// Traffic: Q 32KB + D 128KB per block = 164 MB L2 (was 272); 32 MFMA per 8
// af-loads (was 16).
__global__ __launch_bounds__(256) void maxsim_kernel(
    const u16* __restrict__ qbf, const u16* __restrict__ dbf,
    float* __restrict__ logits)
{
    __shared__ u16 qlds[4 * 4096];     // 32 KB: 4 query-batch fragment tiles
    const int tid  = threadIdx.x;
    const int wid  = tid >> 6;
    const int lane = tid & 63;
    const int soff = ((lane & 31) * 2 + (lane >> 5)) * 8;

    const int qg  = blockIdx.x >> 5;        // 0..31
    const int dg  = blockIdx.x & 31;        // 0..31
    const int qb0 = qg * 4;
    const int dbg = dg * 4 + wid;           // this wave's doc batch

    // stage 32 KB of Q frags (flat copy: frag layout is contiguous per qb)
    {
        const u32x4* src = (const u32x4*)(qbf + (size_t)qb0 * 4096);
        u32x4* dst = (u32x4*)qlds;
        #pragma unroll
        for (int i = 0; i < 8; ++i)
            dst[tid + i * 256] = src[tid + i * 256];
    }
    __syncthreads();

    float rmax[4] = {-3.4e38f, -3.4e38f, -3.4e38f, -3.4e38f};
    const u16* dbase = dbf + (size_t)dbg * 4 * 4096 + soff;

    #pragma unroll
    for (int tile = 0; tile < 4; ++tile) {
        short8 af[8];
        #pragma unroll
        for (int kc = 0; kc < 8; ++kc)
            af[kc] = *(const short8*)(dbase + (size_t)tile * 4096 + kc * 512);

        #pragma unroll
        for (int qp = 0; qp < 2; ++qp) {           // qs pairs for MFMA ILP
            f32x16 a0 = {0.f}, a1 = {0.f};
            #pragma unroll
            for (int kc = 0; kc < 8; ++kc) {
                short8 b0 = *(const short8*)&qlds[(qp*2+0)*4096 + kc*512 + soff];
                short8 b1 = *(const short8*)&qlds[(qp*2+1)*4096 + kc*512 + soff];
                a0 = __builtin_amdgcn_mfma_f32_32x32x16_bf16(af[kc], b0, a0, 0, 0, 0);
                a1 = __builtin_amdgcn_mfma_f32_32x32x16_bf16(af[kc], b1, a1, 0, 0, 0);
            }
            #pragma unroll
            for (int h = 0; h < 2; ++h) {
                const f32x16 a = h ? a1 : a0;
                float m0 = fmaxf(a[0], a[1]),   m1 = fmaxf(a[2], a[3]);
                float m2 = fmaxf(a[4], a[5]),   m3 = fmaxf(a[6], a[7]);
                float m4 = fmaxf(a[8], a[9]),   m5 = fmaxf(a[10], a[11]);
                float m6 = fmaxf(a[12], a[13]), m7 = fmaxf(a[14], a[15]);
                float m = fmaxf(fmaxf(fmaxf(m0, m1), fmaxf(m2, m3)),
                                fmaxf(fmaxf(m4, m5), fmaxf(m6, m7)));
                rmax[qp*2+h] = fmaxf(rmax[qp*2+h], m);
            }
        }
    }

    // cross-half max (rows 16..31 live in lanes 32..63), then sum over q tokens
    #pragma unroll
    for (int qs = 0; qs < 4; ++qs) {
        float v = fmaxf(rmax[qs], __shfl_xor(rmax[qs], 32));
        v += __shfl_xor(v, 1);
        v += __shfl_xor(v, 2);
        v += __shfl_xor(v, 4);
        v += __shfl_xor(v, 8);
        v += __shfl_xor(v, 16);
        if (lane == 0) logits[(size_t)(qb0 + qs) * 128 + dbg] = v;
    }
}

extern "C" void kernel_launch(void* const* d_in, const int* in_sizes, int n_in,
                              void* d_out, int out_size, void* d_ws, size_t ws_size,
                              hipStream_t stream)
{
    const float* query_h = (const float*)d_in[0];  // [128,32,256]
    const float* doc_h   = (const float*)d_in[1];  // [128,128,256]
    const float* W       = (const float*)d_in[2];  // [256,128]
    const float* bias    = (const float*)d_in[3];  // [128]
    float* logits = (float*)d_out;                 // [128,128]

    u16* qbf = (u16*)d_ws;                         // 128 tiles x 4096 (1 MB)
    u16* dbf = qbf + (size_t)128 * 4096;           // 512 tiles x 4096 (4 MB)
    u16* whi = dbf + (size_t)512 * 4096;           // 64 KB
    u16* wlo = whi + (size_t)4096 * 8;             // 64 KB

    prep_w   <<<dim3(16),   dim3(256), 0, stream>>>(W, whi, wlo);
    proj_mfma<<<dim3(640),  dim3(64),  0, stream>>>(query_h, doc_h, bias, whi, wlo, qbf, dbf);
    maxsim_kernel<<<dim3(1024), dim3(256), 0, stream>>>(qbf, dbf, logits);
}

// Round 10
// 103.180 us; speedup vs baseline: 1.0501x; 1.0501x over previous
//
#include <hip/hip_runtime.h>

typedef unsigned short u16;
typedef unsigned int u32;
typedef __attribute__((ext_vector_type(8))) short short8;
typedef __attribute__((ext_vector_type(16))) float f32x16;
typedef __attribute__((ext_vector_type(4))) float f32x4;
typedef __attribute__((ext_vector_type(4))) unsigned int u32x4;

#define H 256
#define D 128

// Fragment-chunk layout for normalized bf16 embeddings (consumed by maxsim):
//   elem index = tile*4096 + kc*512 + (l31*2 + lg2)*8 + j
//   holds Y[token = tile*32 + l31][k = kc*16 + lg2*8 + j]
// A wave's 64 lanes (slot = l31*2+lg2) load/store 1024 CONTIGUOUS bytes per kc.

union V16 { u32x4 u; short8 s; f32x4 f; };

static __device__ inline u32 bf16pk_rne(float a, float b) {
    u32 ua = __float_as_uint(a), ub = __float_as_uint(b);
    ua = ua + 0x7FFFu + ((ua >> 16) & 1u);
    ub = ub + 0x7FFFu + ((ub >> 16) & 1u);
    return (ua >> 16) | (ub & 0xFFFF0000u);
}

// ---------------- proj: LDS-staged X + 3-term bf16-split MFMA ----------------
// grid: 32 (query) + 128 (doc) blocks x 256 thr. Wave handles 32 tokens.
// W hi/lo split is done INLINE (prep_w kernel eliminated): lane (l31,hi) loads
// W[kc*16+hi*8+j][nt*32+l31] (contiguous across l31 -> coalesced), splits into
// bf16 hi (trunc) + lo (RNE of exact residual) — bit-identical to old prep_w.
__global__ __launch_bounds__(256) void proj_mfma(
    const float* __restrict__ Xq, const float* __restrict__ Xd,
    const float* __restrict__ bias, const float* __restrict__ W,
    u16* __restrict__ outq, u16* __restrict__ outd)
{
    __shared__ float xst[4][32][256];   // 128 KB; slot s of row t holds slot s^(t&7)
    const int tid  = threadIdx.x;
    const int wid  = tid >> 6;
    const int lane = tid & 63;
    const int l31  = lane & 31;
    const int hi   = lane >> 5;
    const int slot = l31 * 2 + hi;

    const float* X; u16* out; int trow0;
    if (blockIdx.x < 32) { X = Xq; out = outq; trow0 = blockIdx.x * 128 + wid * 32; }
    else { X = Xd; out = outd; trow0 = (blockIdx.x - 32) * 128 + wid * 32; }

    // ---- stage: 32 rows x 1 KB, coalesced; wave-private (no barrier) ----
    {
        float* xw = &xst[wid][0][0];
        const float* xs0 = X + (size_t)trow0 * H;
        #pragma unroll
        for (int t = 0; t < 32; ++t) {
            f32x4 v = *(const f32x4*)&xs0[(size_t)t * H + lane * 4];
            int sl = lane ^ (t & 7);
            *(f32x4*)&xw[t * 256 + sl * 4] = v;
        }
    }

    f32x16 acc[4];
    #pragma unroll
    for (int nt = 0; nt < 4; ++nt) acc[nt] = (f32x16){0.f};

    // this lane's W column base: row k, col n = nt*32 + l31
    const float* wbase = W + l31;

    const float* xw = &xst[wid][0][0];
    #pragma unroll
    for (int kc = 0; kc < 16; ++kc) {
        const int g = kc * 4 + hi * 2;
        const int sw = l31 & 7;
        f32x4 va = *(const f32x4*)&xw[l31 * 256 + ((g ^ sw) << 2)];
        f32x4 vb = *(const f32x4*)&xw[l31 * 256 + (((g + 1) ^ sw) << 2)];
        float e[8];
        #pragma unroll
        for (int i = 0; i < 4; ++i) { e[i] = va[i]; e[i + 4] = vb[i]; }

        V16 xh, xl;
        u32 xhu[4], xlu[4];
        #pragma unroll
        for (int p = 0; p < 4; ++p) {
            u32 u0 = __float_as_uint(e[2*p]), u1 = __float_as_uint(e[2*p+1]);
            u32 h0 = u0 & 0xFFFF0000u,        h1 = u1 & 0xFFFF0000u;
            xhu[p] = (u0 >> 16) | h1;                          // hi = trunc
            float l0 = e[2*p]   - __uint_as_float(h0);         // exact residual
            float l1 = e[2*p+1] - __uint_as_float(h1);
            xlu[p] = (__float_as_uint(l0) >> 16) |
                     (__float_as_uint(l1) & 0xFFFF0000u);
        }
        xh.u = (u32x4){xhu[0], xhu[1], xhu[2], xhu[3]};
        xl.u = (u32x4){xlu[0], xlu[1], xlu[2], xlu[3]};

        // W rows for this kc: k0 = kc*16 + hi*8 (+j)
        const float* wk = wbase + (size_t)(kc * 16 + hi * 8) * D;

        #pragma unroll
        for (int nt = 0; nt < 4; ++nt) {
            const float* wp = wk + nt * 32;
            u32 hw[4], lw[4];
            #pragma unroll
            for (int p = 0; p < 4; ++p) {
                float a = wp[(size_t)(2*p)     * D];
                float b = wp[(size_t)(2*p + 1) * D];
                u32 ua = __float_as_uint(a), ub = __float_as_uint(b);
                u32 ha = ua & 0xFFFF0000u,   hb = ub & 0xFFFF0000u;
                hw[p] = (ua >> 16) | hb;                       // hi = truncation
                float la = a - __uint_as_float(ha);
                float lb = b - __uint_as_float(hb);
                u32 ra = __float_as_uint(la); ra += 0x7FFFu + ((ra >> 16) & 1u);
                u32 rb = __float_as_uint(lb); rb += 0x7FFFu + ((rb >> 16) & 1u);
                lw[p] = (ra >> 16) | (rb & 0xFFFF0000u);       // lo = RNE bf16
            }
            V16 wh, wl;
            wh.u = (u32x4){hw[0], hw[1], hw[2], hw[3]};
            wl.u = (u32x4){lw[0], lw[1], lw[2], lw[3]};
            acc[nt] = __builtin_amdgcn_mfma_f32_32x32x16_bf16(wh.s, xh.s, acc[nt], 0, 0, 0);
            acc[nt] = __builtin_amdgcn_mfma_f32_32x32x16_bf16(wl.s, xh.s, acc[nt], 0, 0, 0);
            acc[nt] = __builtin_amdgcn_mfma_f32_32x32x16_bf16(wh.s, xl.s, acc[nt], 0, 0, 0);
        }
    }

    // bias + sum-sq (lane holds 64 of token l31's 128 outputs; partner has rest)
    float ss = 0.f;
    #pragma unroll
    for (int nt = 0; nt < 4; ++nt) {
        #pragma unroll
        for (int q = 0; q < 4; ++q) {
            f32x4 b4 = *(const f32x4*)&bias[nt * 32 + q * 8 + hi * 4];
            #pragma unroll
            for (int i = 0; i < 4; ++i) {
                float v = acc[nt][q*4+i] + b4[i];
                acc[nt][q*4+i] = v;
                ss += v * v;
            }
        }
    }
    ss += __shfl_xor(ss, 32);
    const float inv = 1.0f / fmaxf(sqrtf(ss), 1e-12f);

    // pack bf16, pair-exchange (l <-> l+32), coalesced frag-layout stores
    const size_t base = (size_t)(trow0 >> 5) * 4096;
    #pragma unroll
    for (int nt = 0; nt < 4; ++nt) {
        #pragma unroll
        for (int q = 0; q < 4; ++q) {
            float v0 = acc[nt][q*4+0] * inv, v1 = acc[nt][q*4+1] * inv;
            float v2 = acc[nt][q*4+2] * inv, v3 = acc[nt][q*4+3] * inv;
            u32 p0 = bf16pk_rne(v0, v1), p1 = bf16pk_rne(v2, v3);
            u32 r0 = __shfl_xor(p0, 32), r1 = __shfl_xor(p1, 32);
            if ((q & 1) == hi) {
                const int kcs = nt * 2 + (q >> 1);
                u32x4 ck;
                if (hi == 0) ck = (u32x4){p0, p1, r0, r1};
                else         ck = (u32x4){r0, r1, p0, p1};
                *(u32x4*)&out[base + (size_t)kcs * 512 + (size_t)slot * 8] = ck;
            }
        }
    }
}

// ---------------- max-sim (r7 v5, UNCHANGED): coalesced frags + af dbuf ------
#define LOAD_AF(AF, DBI)                                                       \
    {                                                                          \
        const u16* dt_ = dbf + (size_t)((db0 + (DBI)) * 4 + wid) * 4096 + soff;\
        _Pragma("unroll")                                                      \
        for (int kc = 0; kc < 8; ++kc)                                         \
            AF[kc] = *(const short8*)(dt_ + kc * 512);                         \
    }

#define COMPUTE_AF(AF, DBI)                                                    \
    {                                                                          \
        f32x16 acc0 = {0.f}, acc1 = {0.f};                                     \
        _Pragma("unroll")                                                      \
        for (int kc = 0; kc < 8; ++kc) {                                       \
            acc0 = __builtin_amdgcn_mfma_f32_32x32x16_bf16(AF[kc], bq[0][kc],  \
                                                           acc0, 0, 0, 0);     \
            acc1 = __builtin_amdgcn_mfma_f32_32x32x16_bf16(AF[kc], bq[1][kc],  \
                                                           acc1, 0, 0, 0);     \
        }                                                                      \
        _Pragma("unroll")                                                      \
        for (int qs = 0; qs < 2; ++qs) {                                       \
            const f32x16 a = qs ? acc1 : acc0;                                 \
            float m0 = fmaxf(a[0], a[1]),   m1 = fmaxf(a[2], a[3]);            \
            float m2 = fmaxf(a[4], a[5]),   m3 = fmaxf(a[6], a[7]);            \
            float m4 = fmaxf(a[8], a[9]),   m5 = fmaxf(a[10], a[11]);          \
            float m6 = fmaxf(a[12], a[13]), m7 = fmaxf(a[14], a[15]);          \
            float m = fmaxf(fmaxf(fmaxf(m0, m1), fmaxf(m2, m3)),               \
                            fmaxf(fmaxf(m4, m5), fmaxf(m6, m7)));              \
            m = fmaxf(m, __shfl_xor(m, 32));                                   \
            if (lane < 32) smax[wid][DBI][qs][l31] = m;                        \
        }                                                                      \
    }

__global__ __launch_bounds__(256) void maxsim_kernel(
    const u16* __restrict__ qbf, const u16* __restrict__ dbf,
    float* __restrict__ logits)
{
    __shared__ float smax[4][8][2][32];   // [wave][dbi][qs][qcol]
    const int tid  = threadIdx.x;
    const int wid  = tid >> 6;
    const int lane = tid & 63;
    const int l31  = lane & 31;
    const int soff = ((lane & 31) * 2 + (lane >> 5)) * 8;

    const int qb0 = (blockIdx.x >> 4) * 2;
    const int db0 = (blockIdx.x & 15) * 8;

    short8 bq[2][8];
    #pragma unroll
    for (int qs = 0; qs < 2; ++qs) {
        const u16* qb_base = qbf + (size_t)(qb0 + qs) * 4096 + soff;
        #pragma unroll
        for (int kc = 0; kc < 8; ++kc)
            bq[qs][kc] = *(const short8*)(qb_base + kc * 512);
    }

    short8 afA[8], afB[8];
    LOAD_AF(afA, 0);
    #pragma unroll
    for (int dbi = 0; dbi < 8; dbi += 2) {
        LOAD_AF(afB, dbi + 1);
        COMPUTE_AF(afA, dbi);
        if (dbi + 2 < 8) LOAD_AF(afA, dbi + 2);
        COMPUTE_AF(afB, dbi + 1);
    }
    __syncthreads();

    {
        const int dbi = tid >> 5;
        const int col = tid & 31;
        float v0 = fmaxf(fmaxf(smax[0][dbi][0][col], smax[1][dbi][0][col]),
                         fmaxf(smax[2][dbi][0][col], smax[3][dbi][0][col]));
        float v1 = fmaxf(fmaxf(smax[0][dbi][1][col], smax[1][dbi][1][col]),
                         fmaxf(smax[2][dbi][1][col], smax[3][dbi][1][col]));
        v0 += __shfl_xor(v0, 1);  v1 += __shfl_xor(v1, 1);
        v0 += __shfl_xor(v0, 2);  v1 += __shfl_xor(v1, 2);
        v0 += __shfl_xor(v0, 4);  v1 += __shfl_xor(v1, 4);
        v0 += __shfl_xor(v0, 8);  v1 += __shfl_xor(v1, 8);
        v0 += __shfl_xor(v0, 16); v1 += __shfl_xor(v1, 16);
        if (col == 0) {
            logits[(size_t)qb0 * 128 + db0 + dbi]       = v0;
            logits[(size_t)(qb0 + 1) * 128 + db0 + dbi] = v1;
        }
    }
}

extern "C" void kernel_launch(void* const* d_in, const int* in_sizes, int n_in,
                              void* d_out, int out_size, void* d_ws, size_t ws_size,
                              hipStream_t stream)
{
    const float* query_h = (const float*)d_in[0];  // [128,32,256]
    const float* doc_h   = (const float*)d_in[1];  // [128,128,256]
    const float* W       = (const float*)d_in[2];  // [256,128]
    const float* bias    = (const float*)d_in[3];  // [128]
    float* logits = (float*)d_out;                 // [128,128]

    u16* qbf = (u16*)d_ws;                         // 128 tiles x 4096 (1 MB)
    u16* dbf = qbf + (size_t)128 * 4096;           // 512 tiles x 4096 (4 MB)

    proj_mfma<<<dim3(160),  dim3(256), 0, stream>>>(query_h, doc_h, bias, W, qbf, dbf);
    maxsim_kernel<<<dim3(1024), dim3(256), 0, stream>>>(qbf, dbf, logits);
}